// Round 2
// baseline (649.041 us; speedup 1.0000x reference)
//
#include <hip/hip_runtime.h>
#include <math.h>

#define NN 50000
#define EE 850000
#define IN_DIM 256
#define HID 32
#define H1 8
#define OUT_DIM 64
#define NEG_SLOPE 0.2f

// ---------------- CSR build ----------------

__global__ __launch_bounds__(256) void k_hist(const int* __restrict__ dst,
                                              int* __restrict__ cnt) {
    int e = blockIdx.x * 256 + threadIdx.x;
    if (e < EE) atomicAdd(&cnt[dst[e]], 1);
}

// single-block exclusive scan over N counts -> row_ptr[N+1]
__global__ __launch_bounds__(1024) void k_scan(const int* __restrict__ cnt,
                                               int* __restrict__ row_ptr) {
    __shared__ int sums[1024];
    int t = threadIdx.x;
    const int CH = (NN + 1023) / 1024;  // 49
    int lo = t * CH, hi = lo + CH;
    if (lo > NN) lo = NN;
    if (hi > NN) hi = NN;
    int s = 0;
    for (int i = lo; i < hi; ++i) s += cnt[i];
    sums[t] = s;
    __syncthreads();
    for (int off = 1; off < 1024; off <<= 1) {
        int v = (t >= off) ? sums[t - off] : 0;
        __syncthreads();
        sums[t] += v;
        __syncthreads();
    }
    int run = (t > 0) ? sums[t - 1] : 0;
    for (int i = lo; i < hi; ++i) {
        row_ptr[i] = run;
        run += cnt[i];
    }
    if (t == 1023) row_ptr[NN] = run;  // == EE
}

__global__ __launch_bounds__(256) void k_scatter(const int* __restrict__ src,
                                                 const int* __restrict__ dst,
                                                 const int* __restrict__ row_ptr,
                                                 int* __restrict__ fill,
                                                 int* __restrict__ esrc) {
    int e = blockIdx.x * 256 + threadIdx.x;
    if (e >= EE) return;
    int d = dst[e];
    int pos = row_ptr[d] + atomicAdd(&fill[d], 1);
    esrc[pos] = src[e];
}

// ---------------- GEMM 64x64 tile (layer 2: Ncols=64) ----------------

__global__ __launch_bounds__(256) void k_gemm(const float* __restrict__ A,
                                              const float* __restrict__ B,
                                              float* __restrict__ C,
                                              int Mrows, int Ncols) {
    const int K = 256;
    __shared__ float As[16][64];  // [k][m]
    __shared__ float Bs[16][64];  // [k][n]
    int tid = threadIdx.x;
    int tx = tid & 15;  // n
    int ty = tid >> 4;  // m
    int row0 = blockIdx.x * 64;
    int col0 = blockIdx.y * 64;
    int lam = tid >> 2;         // 0..63 row in A tile
    int lak = (tid & 3) * 4;    // k offset
    int lbk = tid >> 4;         // 0..15 k row in B tile
    int lbn = (tid & 15) * 4;   // n offset
    float acc[4][4] = {};
    for (int k0 = 0; k0 < K; k0 += 16) {
        float4 av = {0.f, 0.f, 0.f, 0.f};
        int ar = row0 + lam;
        if (ar < Mrows) av = *(const float4*)(A + (size_t)ar * K + k0 + lak);
        As[lak + 0][lam] = av.x;
        As[lak + 1][lam] = av.y;
        As[lak + 2][lam] = av.z;
        As[lak + 3][lam] = av.w;
        float4 bv = *(const float4*)(B + (size_t)(k0 + lbk) * Ncols + col0 + lbn);
        *(float4*)&Bs[lbk][lbn] = bv;
        __syncthreads();
#pragma unroll
        for (int k = 0; k < 16; ++k) {
            float4 ra = *(const float4*)&As[k][ty * 4];
            float4 rb = *(const float4*)&Bs[k][tx * 4];
            float a4[4] = {ra.x, ra.y, ra.z, ra.w};
            float b4[4] = {rb.x, rb.y, rb.z, rb.w};
#pragma unroll
            for (int um = 0; um < 4; ++um)
#pragma unroll
                for (int un = 0; un < 4; ++un) acc[um][un] += a4[um] * b4[un];
        }
        __syncthreads();
    }
#pragma unroll
    for (int um = 0; um < 4; ++um) {
        int r = row0 + ty * 4 + um;
        if (r < Mrows) {
            float4 v = {acc[um][0], acc[um][1], acc[um][2], acc[um][3]};
            *(float4*)(C + (size_t)r * Ncols + col0 + tx * 4) = v;
        }
    }
}

// ---------------- GEMM 128x128 tile, 8x8 micro (layer 1: Ncols=256) --------
// VALU:LDS per k-step = 128cy : ~48cy -> VALU-bound (~80% issue achievable)

__global__ __launch_bounds__(256) void k_gemm128(const float* __restrict__ A,
                                                 const float* __restrict__ B,
                                                 float* __restrict__ C,
                                                 int Mrows, int Ncols) {
    const int K = 256;
    __shared__ float As[16][128];
    __shared__ float Bs[16][128];
    int tid = threadIdx.x;
    int tx = tid & 15;   // n quad
    int ty = tid >> 4;   // m quad
    int row0 = blockIdx.x * 128;
    int col0 = blockIdx.y * 128;
    int lam = tid >> 1;          // 0..127 (row of A tile)
    int lak = (tid & 1) * 8;     // 0 or 8 (k offset, 8 floats)
    int lbk = tid >> 4;          // 0..15 (k row of B tile)
    int lbn = (tid & 15) * 8;    // 0..120 (col offset, 8 floats)
    float acc[2][2][4][4] = {};
    for (int k0 = 0; k0 < K; k0 += 16) {
        int ar = row0 + lam;
        float4 av0 = {0.f, 0.f, 0.f, 0.f}, av1 = {0.f, 0.f, 0.f, 0.f};
        if (ar < Mrows) {
            const float* ap = A + (size_t)ar * K + k0 + lak;
            av0 = *(const float4*)(ap);
            av1 = *(const float4*)(ap + 4);
        }
        As[lak + 0][lam] = av0.x;
        As[lak + 1][lam] = av0.y;
        As[lak + 2][lam] = av0.z;
        As[lak + 3][lam] = av0.w;
        As[lak + 4][lam] = av1.x;
        As[lak + 5][lam] = av1.y;
        As[lak + 6][lam] = av1.z;
        As[lak + 7][lam] = av1.w;
        const float* bp = B + (size_t)(k0 + lbk) * Ncols + col0 + lbn;
        *(float4*)&Bs[lbk][lbn] = *(const float4*)(bp);
        *(float4*)&Bs[lbk][lbn + 4] = *(const float4*)(bp + 4);
        __syncthreads();
#pragma unroll
        for (int k = 0; k < 16; ++k) {
            float4 a0 = *(const float4*)&As[k][ty * 4];
            float4 a1 = *(const float4*)&As[k][ty * 4 + 64];
            float4 b0 = *(const float4*)&Bs[k][tx * 4];
            float4 b1 = *(const float4*)&Bs[k][tx * 4 + 64];
            float am[2][4] = {{a0.x, a0.y, a0.z, a0.w}, {a1.x, a1.y, a1.z, a1.w}};
            float bn[2][4] = {{b0.x, b0.y, b0.z, b0.w}, {b1.x, b1.y, b1.z, b1.w}};
#pragma unroll
            for (int im = 0; im < 2; ++im)
#pragma unroll
                for (int jn = 0; jn < 2; ++jn)
#pragma unroll
                    for (int um = 0; um < 4; ++um)
#pragma unroll
                        for (int un = 0; un < 4; ++un)
                            acc[im][jn][um][un] += am[im][um] * bn[jn][un];
        }
        __syncthreads();
    }
#pragma unroll
    for (int im = 0; im < 2; ++im)
#pragma unroll
        for (int um = 0; um < 4; ++um) {
            int r = row0 + im * 64 + ty * 4 + um;
            if (r < Mrows) {
#pragma unroll
                for (int jn = 0; jn < 2; ++jn) {
                    float4 v = {acc[im][jn][um][0], acc[im][jn][um][1],
                                acc[im][jn][um][2], acc[im][jn][um][3]};
                    *(float4*)(C + (size_t)r * Ncols + col0 + jn * 64 + tx * 4) = v;
                }
            }
        }
}

// ---------------- el/er: per (node, head) dot with al/ar ----------------

template <int H, int D>
__global__ __launch_bounds__(256) void k_el_er(const float* __restrict__ feat,
                                               const float* __restrict__ al,
                                               const float* __restrict__ ar,
                                               float* __restrict__ el,
                                               float* __restrict__ er) {
    int idx = blockIdx.x * 256 + threadIdx.x;
    if (idx >= NN * H) return;
    int i = idx / H, hh = idx % H;
    const float* fp = feat + (size_t)i * (H * D) + hh * D;
    float sl = 0.f, sr = 0.f;
#pragma unroll
    for (int d = 0; d < D; d += 4) {
        float4 v = *(const float4*)(fp + d);
        sl += v.x * al[hh * D + d] + v.y * al[hh * D + d + 1] +
              v.z * al[hh * D + d + 2] + v.w * al[hh * D + d + 3];
        sr += v.x * ar[hh * D + d] + v.y * ar[hh * D + d + 1] +
              v.z * ar[hh * D + d + 2] + v.w * ar[hh * D + d + 3];
    }
    el[idx] = sl;
    er[idx] = sr;
}

// ---------------- per-(node,head) online softmax stats ----------------

template <int H>
__global__ __launch_bounds__(256) void k_stats(const float* __restrict__ el,
                                               const float* __restrict__ er,
                                               const int* __restrict__ rp,
                                               const int* __restrict__ esrc,
                                               float* __restrict__ mo,
                                               float* __restrict__ io) {
    int idx = blockIdx.x * 256 + threadIdx.x;
    if (idx >= NN * H) return;
    int i = idx / H, hh = idx % H;
    float eri = er[idx];
    int lo = rp[i], hi = rp[i + 1];
    float m = -INFINITY, s = 0.f;
    for (int j = lo; j < hi; ++j) {
        int sn = esrc[j];
        float x = el[sn * H + hh] + eri;
        x = (x >= 0.f) ? x : NEG_SLOPE * x;
        if (x > m) {
            s = s * __expf(m - x) + 1.f;
            m = x;
        } else {
            s += __expf(x - m);
        }
    }
    mo[idx] = m;
    io[idx] = 1.f / s;
}

// ---------------- layer-1 aggregation: block(256) per dst node ----------------
// t = h*32 + d ; fused bias + ELU epilogue -> h1

__global__ __launch_bounds__(256) void k_agg1(const float* __restrict__ feat,
                                              const float* __restrict__ el,
                                              const float* __restrict__ er,
                                              const float* __restrict__ mm,
                                              const float* __restrict__ iv,
                                              const int* __restrict__ rp,
                                              const int* __restrict__ esrc,
                                              const float* __restrict__ bias,
                                              float* __restrict__ out) {
    __shared__ float alpha_s[32][8];
    __shared__ int src_s[32];
    int i = blockIdx.x;
    int t = threadIdx.x;
    int hh = t >> 5, dd = t & 31;
    int lo = rp[i], hi = rp[i + 1];
    float er_i = er[i * 8 + hh];
    float m_i = mm[i * 8 + hh];
    float iv_i = iv[i * 8 + hh];
    float acc = 0.f;
    for (int j0 = lo; j0 < hi; j0 += 32) {
        __syncthreads();
        int j = j0 + dd;  // thread (hh, dd) computes alpha for edge j0+dd, head hh
        float a = 0.f;
        int sn = 0;
        if (j < hi) {
            sn = esrc[j];
            float x = el[sn * 8 + hh] + er_i;
            x = (x >= 0.f) ? x : NEG_SLOPE * x;
            a = __expf(x - m_i) * iv_i;
        }
        if (hh == 0) src_s[dd] = sn;
        alpha_s[dd][hh] = a;
        __syncthreads();
        int cnt = hi - j0;
        if (cnt > 32) cnt = 32;
        for (int jj = 0; jj < cnt; ++jj) {
            acc += feat[(size_t)src_s[jj] * 256 + t] * alpha_s[jj][hh];
        }
    }
    float v = acc + bias[t];
    out[(size_t)i * 256 + t] = (v > 0.f) ? v : (__expf(v) - 1.f);
}

// ---------------- layer-2 aggregation: one wave per dst node ----------------

__global__ __launch_bounds__(256) void k_agg2(const float* __restrict__ feat2,
                                              const float* __restrict__ el2,
                                              const float* __restrict__ er2,
                                              const float* __restrict__ m2,
                                              const float* __restrict__ iv2,
                                              const int* __restrict__ rp,
                                              const int* __restrict__ esrc,
                                              const float* __restrict__ b2,
                                              float* __restrict__ out) {
    int wid = threadIdx.x >> 6;
    int lane = threadIdx.x & 63;
    int i = blockIdx.x * 4 + wid;
    if (i >= NN) return;
    int lo = rp[i], hi = rp[i + 1];
    float er_i = er2[i], m_i = m2[i], iv_i = iv2[i];
    float acc = 0.f;
    for (int j = lo; j < hi; ++j) {
        int sn = esrc[j];
        float x = el2[sn] + er_i;
        x = (x >= 0.f) ? x : NEG_SLOPE * x;
        float a = __expf(x - m_i) * iv_i;
        acc += feat2[(size_t)sn * 64 + lane] * a;
    }
    out[(size_t)i * 64 + lane] = acc + b2[lane];
}

// ---------------- launch ----------------

extern "C" void kernel_launch(void* const* d_in, const int* in_sizes, int n_in,
                              void* d_out, int out_size, void* d_ws, size_t ws_size,
                              hipStream_t stream) {
    const float* h   = (const float*)d_in[0];
    const float* W1  = (const float*)d_in[1];
    const float* al1 = (const float*)d_in[2];
    const float* ar1 = (const float*)d_in[3];
    const float* b1  = (const float*)d_in[4];
    const float* W2  = (const float*)d_in[5];
    const float* al2 = (const float*)d_in[6];
    const float* ar2 = (const float*)d_in[7];
    const float* b2  = (const float*)d_in[8];
    const int* src   = (const int*)d_in[9];
    const int* dst   = (const int*)d_in[10];
    float* out = (float*)d_out;

    // workspace carve (~110 MB)
    float* fp = (float*)d_ws;
    float* feat1 = fp; fp += (size_t)NN * 256;   // feat2 aliases feat1 (feat1 dead after k_agg1)
    float* h1    = fp; fp += (size_t)NN * 256;
    float* el1 = fp; fp += (size_t)NN * 8;
    float* er1 = fp; fp += (size_t)NN * 8;
    float* m1  = fp; fp += (size_t)NN * 8;
    float* iv1 = fp; fp += (size_t)NN * 8;
    float* el2 = fp; fp += NN;
    float* er2 = fp; fp += NN;
    float* m2  = fp; fp += NN;
    float* iv2 = fp; fp += NN;
    float* feat2 = feat1;
    int* ip = (int*)fp;
    int* row_ptr = ip; ip += NN + 1;
    int* cnt  = ip; ip += NN;
    int* fill = ip; ip += NN;   // adjacent to cnt: single memset covers both
    int* esrc = ip; ip += EE;

    hipMemsetAsync(cnt, 0, sizeof(int) * 2 * NN, stream);

    // CSR by dst
    k_hist<<<(EE + 255) / 256, 256, 0, stream>>>(dst, cnt);
    k_scan<<<1, 1024, 0, stream>>>(cnt, row_ptr);
    k_scatter<<<(EE + 255) / 256, 256, 0, stream>>>(src, dst, row_ptr, fill, esrc);

    // layer 1
    dim3 g1((NN + 127) / 128, 256 / 128);
    k_gemm128<<<g1, 256, 0, stream>>>(h, W1, feat1, NN, 256);
    k_el_er<8, 32><<<(NN * 8 + 255) / 256, 256, 0, stream>>>(feat1, al1, ar1, el1, er1);
    k_stats<8><<<(NN * 8 + 255) / 256, 256, 0, stream>>>(el1, er1, row_ptr, esrc, m1, iv1);
    k_agg1<<<NN, 256, 0, stream>>>(feat1, el1, er1, m1, iv1, row_ptr, esrc, b1, h1);

    // layer 2
    dim3 g2((NN + 63) / 64, 64 / 64);
    k_gemm<<<g2, 256, 0, stream>>>(h1, W2, feat2, NN, 64);
    k_el_er<1, 64><<<(NN + 255) / 256, 256, 0, stream>>>(feat2, al2, ar2, el2, er2);
    k_stats<1><<<(NN + 255) / 256, 256, 0, stream>>>(el2, er2, row_ptr, esrc, m2, iv2);
    k_agg2<<<(NN + 3) / 4, 256, 0, stream>>>(feat2, el2, er2, m2, iv2, row_ptr, esrc, b2, out);
}

// Round 3
// 607.530 us; speedup vs baseline: 1.0683x; 1.0683x over previous
//
#include <hip/hip_runtime.h>
#include <math.h>

#define NN 50000
#define EE 850000
#define IN_DIM 256
#define HID 32
#define H1 8
#define OUT_DIM 64
#define NEG_SLOPE 0.2f

// ---------------- CSR build ----------------

__global__ __launch_bounds__(256) void k_hist(const int* __restrict__ dst,
                                              int* __restrict__ cnt) {
    int e = blockIdx.x * 256 + threadIdx.x;
    if (e < EE) atomicAdd(&cnt[dst[e]], 1);
}

// single-block exclusive scan over N counts -> row_ptr[N+1]
__global__ __launch_bounds__(1024) void k_scan(const int* __restrict__ cnt,
                                               int* __restrict__ row_ptr) {
    __shared__ int sums[1024];
    int t = threadIdx.x;
    const int CH = (NN + 1023) / 1024;  // 49
    int lo = t * CH, hi = lo + CH;
    if (lo > NN) lo = NN;
    if (hi > NN) hi = NN;
    int s = 0;
    for (int i = lo; i < hi; ++i) s += cnt[i];
    sums[t] = s;
    __syncthreads();
    for (int off = 1; off < 1024; off <<= 1) {
        int v = (t >= off) ? sums[t - off] : 0;
        __syncthreads();
        sums[t] += v;
        __syncthreads();
    }
    int run = (t > 0) ? sums[t - 1] : 0;
    for (int i = lo; i < hi; ++i) {
        row_ptr[i] = run;
        run += cnt[i];
    }
    if (t == 1023) row_ptr[NN] = run;  // == EE
}

__global__ __launch_bounds__(256) void k_scatter(const int* __restrict__ src,
                                                 const int* __restrict__ dst,
                                                 const int* __restrict__ row_ptr,
                                                 int* __restrict__ fill,
                                                 int* __restrict__ esrc) {
    int e = blockIdx.x * 256 + threadIdx.x;
    if (e >= EE) return;
    int d = dst[e];
    int pos = row_ptr[d] + atomicAdd(&fill[d], 1);
    esrc[pos] = src[e];
}

// ---------------- GEMM 64x64 tile (layer 2: Ncols=64) ----------------

__global__ __launch_bounds__(256) void k_gemm(const float* __restrict__ A,
                                              const float* __restrict__ B,
                                              float* __restrict__ C,
                                              int Mrows, int Ncols) {
    const int K = 256;
    __shared__ float As[16][64];  // [k][m]
    __shared__ float Bs[16][64];  // [k][n]
    int tid = threadIdx.x;
    int tx = tid & 15;  // n
    int ty = tid >> 4;  // m
    int row0 = blockIdx.x * 64;
    int col0 = blockIdx.y * 64;
    int lam = tid >> 2;         // 0..63 row in A tile
    int lak = (tid & 3) * 4;    // k offset
    int lbk = tid >> 4;         // 0..15 k row in B tile
    int lbn = (tid & 15) * 4;   // n offset
    float acc[4][4] = {};
    for (int k0 = 0; k0 < K; k0 += 16) {
        float4 av = {0.f, 0.f, 0.f, 0.f};
        int ar = row0 + lam;
        if (ar < Mrows) av = *(const float4*)(A + (size_t)ar * K + k0 + lak);
        As[lak + 0][lam] = av.x;
        As[lak + 1][lam] = av.y;
        As[lak + 2][lam] = av.z;
        As[lak + 3][lam] = av.w;
        float4 bv = *(const float4*)(B + (size_t)(k0 + lbk) * Ncols + col0 + lbn);
        *(float4*)&Bs[lbk][lbn] = bv;
        __syncthreads();
#pragma unroll
        for (int k = 0; k < 16; ++k) {
            float4 ra = *(const float4*)&As[k][ty * 4];
            float4 rb = *(const float4*)&Bs[k][tx * 4];
            float a4[4] = {ra.x, ra.y, ra.z, ra.w};
            float b4[4] = {rb.x, rb.y, rb.z, rb.w};
#pragma unroll
            for (int um = 0; um < 4; ++um)
#pragma unroll
                for (int un = 0; un < 4; ++un) acc[um][un] += a4[um] * b4[un];
        }
        __syncthreads();
    }
#pragma unroll
    for (int um = 0; um < 4; ++um) {
        int r = row0 + ty * 4 + um;
        if (r < Mrows) {
            float4 v = {acc[um][0], acc[um][1], acc[um][2], acc[um][3]};
            *(float4*)(C + (size_t)r * Ncols + col0 + tx * 4) = v;
        }
    }
}

// ---------------- GEMM 128x128 tile, 8x8 micro (layer 1: Ncols=256) --------

__global__ __launch_bounds__(256) void k_gemm128(const float* __restrict__ A,
                                                 const float* __restrict__ B,
                                                 float* __restrict__ C,
                                                 int Mrows, int Ncols) {
    const int K = 256;
    __shared__ float As[16][128];
    __shared__ float Bs[16][128];
    int tid = threadIdx.x;
    int tx = tid & 15;   // n quad
    int ty = tid >> 4;   // m quad
    int row0 = blockIdx.x * 128;
    int col0 = blockIdx.y * 128;
    int lam = tid >> 1;          // 0..127 (row of A tile)
    int lak = (tid & 1) * 8;     // 0 or 8 (k offset, 8 floats)
    int lbk = tid >> 4;          // 0..15 (k row of B tile)
    int lbn = (tid & 15) * 8;    // 0..120 (col offset, 8 floats)
    float acc[2][2][4][4] = {};
    for (int k0 = 0; k0 < K; k0 += 16) {
        int ar = row0 + lam;
        float4 av0 = {0.f, 0.f, 0.f, 0.f}, av1 = {0.f, 0.f, 0.f, 0.f};
        if (ar < Mrows) {
            const float* ap = A + (size_t)ar * K + k0 + lak;
            av0 = *(const float4*)(ap);
            av1 = *(const float4*)(ap + 4);
        }
        As[lak + 0][lam] = av0.x;
        As[lak + 1][lam] = av0.y;
        As[lak + 2][lam] = av0.z;
        As[lak + 3][lam] = av0.w;
        As[lak + 4][lam] = av1.x;
        As[lak + 5][lam] = av1.y;
        As[lak + 6][lam] = av1.z;
        As[lak + 7][lam] = av1.w;
        const float* bp = B + (size_t)(k0 + lbk) * Ncols + col0 + lbn;
        *(float4*)&Bs[lbk][lbn] = *(const float4*)(bp);
        *(float4*)&Bs[lbk][lbn + 4] = *(const float4*)(bp + 4);
        __syncthreads();
#pragma unroll
        for (int k = 0; k < 16; ++k) {
            float4 a0 = *(const float4*)&As[k][ty * 4];
            float4 a1 = *(const float4*)&As[k][ty * 4 + 64];
            float4 b0 = *(const float4*)&Bs[k][tx * 4];
            float4 b1 = *(const float4*)&Bs[k][tx * 4 + 64];
            float am[2][4] = {{a0.x, a0.y, a0.z, a0.w}, {a1.x, a1.y, a1.z, a1.w}};
            float bn[2][4] = {{b0.x, b0.y, b0.z, b0.w}, {b1.x, b1.y, b1.z, b1.w}};
#pragma unroll
            for (int im = 0; im < 2; ++im)
#pragma unroll
                for (int jn = 0; jn < 2; ++jn)
#pragma unroll
                    for (int um = 0; um < 4; ++um)
#pragma unroll
                        for (int un = 0; un < 4; ++un)
                            acc[im][jn][um][un] += am[im][um] * bn[jn][un];
        }
        __syncthreads();
    }
#pragma unroll
    for (int im = 0; im < 2; ++im)
#pragma unroll
        for (int um = 0; um < 4; ++um) {
            int r = row0 + im * 64 + ty * 4 + um;
            if (r < Mrows) {
#pragma unroll
                for (int jn = 0; jn < 2; ++jn) {
                    float4 v = {acc[im][jn][um][0], acc[im][jn][um][1],
                                acc[im][jn][um][2], acc[im][jn][um][3]};
                    *(float4*)(C + (size_t)r * Ncols + col0 + jn * 64 + tx * 4) = v;
                }
            }
        }
}

// ---------------- el/er: per (node, head) dot with al/ar ----------------

template <int H, int D>
__global__ __launch_bounds__(256) void k_el_er(const float* __restrict__ feat,
                                               const float* __restrict__ al,
                                               const float* __restrict__ ar,
                                               float* __restrict__ el,
                                               float* __restrict__ er) {
    int idx = blockIdx.x * 256 + threadIdx.x;
    if (idx >= NN * H) return;
    int i = idx / H, hh = idx % H;
    const float* fp = feat + (size_t)i * (H * D) + hh * D;
    float sl = 0.f, sr = 0.f;
#pragma unroll
    for (int d = 0; d < D; d += 4) {
        float4 v = *(const float4*)(fp + d);
        sl += v.x * al[hh * D + d] + v.y * al[hh * D + d + 1] +
              v.z * al[hh * D + d + 2] + v.w * al[hh * D + d + 3];
        sr += v.x * ar[hh * D + d] + v.y * ar[hh * D + d + 1] +
              v.z * ar[hh * D + d + 2] + v.w * ar[hh * D + d + 3];
    }
    el[idx] = sl;
    er[idx] = sr;
}

// ---------------- layer-1 fused online-softmax aggregation ----------------
// one wave per dst node; lane l owns channels 4l..4l+3 (head = l>>3).
// flash-style: running m, s, acc; final v = acc/s + bias, then ELU.

__global__ __launch_bounds__(256) void k_agg1(const float* __restrict__ feat,
                                              const float* __restrict__ el,
                                              const float* __restrict__ er,
                                              const int* __restrict__ rp,
                                              const int* __restrict__ esrc,
                                              const float* __restrict__ bias,
                                              float* __restrict__ out) {
    int wid = threadIdx.x >> 6;
    int lane = threadIdx.x & 63;
    int i = blockIdx.x * 4 + wid;
    if (i >= NN) return;
    int hh = lane >> 3;
    float er_i = er[i * 8 + hh];
    int lo = rp[i], hi = rp[i + 1];
    float m = -INFINITY, s = 0.f;
    float4 acc = {0.f, 0.f, 0.f, 0.f};
    for (int j = lo; j < hi; ++j) {
        int sn = esrc[j];
        float x = el[sn * 8 + hh] + er_i;
        x = (x >= 0.f) ? x : NEG_SLOPE * x;
        float w;
        if (x > m) {
            float r = __expf(m - x);  // exp(-inf)=0 on first edge
            s = s * r + 1.f;
            acc.x *= r; acc.y *= r; acc.z *= r; acc.w *= r;
            m = x;
            w = 1.f;
        } else {
            w = __expf(x - m);
            s += w;
        }
        float4 f = *(const float4*)(feat + (size_t)sn * 256 + lane * 4);
        acc.x += f.x * w; acc.y += f.y * w; acc.z += f.z * w; acc.w += f.w * w;
    }
    float inv = 1.f / s;
    const float4 b = *(const float4*)(bias + lane * 4);
    float4 v = {acc.x * inv + b.x, acc.y * inv + b.y,
                acc.z * inv + b.z, acc.w * inv + b.w};
    v.x = (v.x > 0.f) ? v.x : (__expf(v.x) - 1.f);
    v.y = (v.y > 0.f) ? v.y : (__expf(v.y) - 1.f);
    v.z = (v.z > 0.f) ? v.z : (__expf(v.z) - 1.f);
    v.w = (v.w > 0.f) ? v.w : (__expf(v.w) - 1.f);
    *(float4*)(out + (size_t)i * 256 + lane * 4) = v;
}

// ---------------- layer-2 fused online-softmax aggregation ----------------
// one wave per dst node; 4 edge-groups of 16 lanes (float4 over 64 channels);
// guarded (m,s,acc) merge across groups via shfl_xor 16,32.

__global__ __launch_bounds__(256) void k_agg2(const float* __restrict__ feat2,
                                              const float* __restrict__ el2,
                                              const float* __restrict__ er2,
                                              const int* __restrict__ rp,
                                              const int* __restrict__ esrc,
                                              const float* __restrict__ b2,
                                              float* __restrict__ out) {
    int wid = threadIdx.x >> 6;
    int lane = threadIdx.x & 63;
    int i = blockIdx.x * 4 + wid;
    if (i >= NN) return;
    int g = lane >> 4;   // edge group 0..3
    int c = lane & 15;   // channel quad
    int lo = rp[i], hi = rp[i + 1];
    float er_i = er2[i];
    float m = -INFINITY, s = 0.f;
    float4 acc = {0.f, 0.f, 0.f, 0.f};
    for (int j0 = lo; j0 < hi; j0 += 4) {
        int j = j0 + g;
        if (j < hi) {
            int sn = esrc[j];
            float x = el2[sn] + er_i;
            x = (x >= 0.f) ? x : NEG_SLOPE * x;
            float w;
            if (x > m) {
                float r = __expf(m - x);
                s = s * r + 1.f;
                acc.x *= r; acc.y *= r; acc.z *= r; acc.w *= r;
                m = x;
                w = 1.f;
            } else {
                w = __expf(x - m);
                s += w;
            }
            const float4 f = *(const float4*)(feat2 + (size_t)sn * 64 + c * 4);
            acc.x += f.x * w; acc.y += f.y * w; acc.z += f.z * w; acc.w += f.w * w;
        }
    }
    // merge (m, s, acc) across the 4 groups
#pragma unroll
    for (int off = 16; off < 64; off <<= 1) {
        float mo = __shfl_xor(m, off);
        float so = __shfl_xor(s, off);
        float4 ao;
        ao.x = __shfl_xor(acc.x, off);
        ao.y = __shfl_xor(acc.y, off);
        ao.z = __shfl_xor(acc.z, off);
        ao.w = __shfl_xor(acc.w, off);
        float M = fmaxf(m, mo);
        float w0 = (m == -INFINITY) ? 0.f : __expf(m - M);
        float w1 = (mo == -INFINITY) ? 0.f : __expf(mo - M);
        s = s * w0 + so * w1;
        acc.x = acc.x * w0 + ao.x * w1;
        acc.y = acc.y * w0 + ao.y * w1;
        acc.z = acc.z * w0 + ao.z * w1;
        acc.w = acc.w * w0 + ao.w * w1;
        m = M;
    }
    if (g == 0) {
        float inv = 1.f / s;
        const float4 b = *(const float4*)(b2 + c * 4);
        float4 v = {acc.x * inv + b.x, acc.y * inv + b.y,
                    acc.z * inv + b.z, acc.w * inv + b.w};
        *(float4*)(out + (size_t)i * 64 + c * 4) = v;
    }
}

// ---------------- launch ----------------

extern "C" void kernel_launch(void* const* d_in, const int* in_sizes, int n_in,
                              void* d_out, int out_size, void* d_ws, size_t ws_size,
                              hipStream_t stream) {
    const float* h   = (const float*)d_in[0];
    const float* W1  = (const float*)d_in[1];
    const float* al1 = (const float*)d_in[2];
    const float* ar1 = (const float*)d_in[3];
    const float* b1  = (const float*)d_in[4];
    const float* W2  = (const float*)d_in[5];
    const float* al2 = (const float*)d_in[6];
    const float* ar2 = (const float*)d_in[7];
    const float* b2  = (const float*)d_in[8];
    const int* src   = (const int*)d_in[9];
    const int* dst   = (const int*)d_in[10];
    float* out = (float*)d_out;

    // workspace carve
    float* fp = (float*)d_ws;
    float* feat1 = fp; fp += (size_t)NN * 256;   // feat2 aliases feat1 (dead after k_agg1)
    float* h1    = fp; fp += (size_t)NN * 256;
    float* el1 = fp; fp += (size_t)NN * 8;
    float* er1 = fp; fp += (size_t)NN * 8;
    float* el2 = fp; fp += NN;
    float* er2 = fp; fp += NN;
    float* feat2 = feat1;
    int* ip = (int*)fp;
    int* row_ptr = ip; ip += NN + 1;
    int* cnt  = ip; ip += NN;
    int* fill = ip; ip += NN;   // adjacent to cnt: single memset covers both
    int* esrc = ip; ip += EE;

    hipMemsetAsync(cnt, 0, sizeof(int) * 2 * NN, stream);

    // CSR by dst
    k_hist<<<(EE + 255) / 256, 256, 0, stream>>>(dst, cnt);
    k_scan<<<1, 1024, 0, stream>>>(cnt, row_ptr);
    k_scatter<<<(EE + 255) / 256, 256, 0, stream>>>(src, dst, row_ptr, fill, esrc);

    // layer 1
    dim3 g1((NN + 127) / 128, 256 / 128);
    k_gemm128<<<g1, 256, 0, stream>>>(h, W1, feat1, NN, 256);
    k_el_er<8, 32><<<(NN * 8 + 255) / 256, 256, 0, stream>>>(feat1, al1, ar1, el1, er1);
    k_agg1<<<(NN + 3) / 4, 256, 0, stream>>>(feat1, el1, er1, row_ptr, esrc, b1, h1);

    // layer 2
    dim3 g2((NN + 63) / 64, 64 / 64);
    k_gemm<<<g2, 256, 0, stream>>>(h1, W2, feat2, NN, 64);
    k_el_er<1, 64><<<(NN + 255) / 256, 256, 0, stream>>>(feat2, al2, ar2, el2, er2);
    k_agg2<<<(NN + 3) / 4, 256, 0, stream>>>(feat2, el2, er2, row_ptr, esrc, b2, out);
}

// Round 8
// 574.683 us; speedup vs baseline: 1.1294x; 1.0572x over previous
//
#include <hip/hip_runtime.h>
#include <math.h>

#define NN 50000
#define EE 850000
#define IN_DIM 256
#define HID 32
#define H1 8
#define OUT_DIM 64
#define NEG_SLOPE 0.2f

// ---------------- CSR build ----------------

__global__ __launch_bounds__(256) void k_hist(const int* __restrict__ dst,
                                              int* __restrict__ cnt) {
    int e = blockIdx.x * 256 + threadIdx.x;
    if (e < EE) atomicAdd(&cnt[dst[e]], 1);
}

// single-block exclusive scan over N counts -> row_ptr[N+1]
__global__ __launch_bounds__(1024) void k_scan(const int* __restrict__ cnt,
                                               int* __restrict__ row_ptr) {
    __shared__ int sums[1024];
    int t = threadIdx.x;
    const int CH = (NN + 1023) / 1024;  // 49
    int lo = t * CH, hi = lo + CH;
    if (lo > NN) lo = NN;
    if (hi > NN) hi = NN;
    int s = 0;
    for (int i = lo; i < hi; ++i) s += cnt[i];
    sums[t] = s;
    __syncthreads();
    for (int off = 1; off < 1024; off <<= 1) {
        int v = (t >= off) ? sums[t - off] : 0;
        __syncthreads();
        sums[t] += v;
        __syncthreads();
    }
    int run = (t > 0) ? sums[t - 1] : 0;
    for (int i = lo; i < hi; ++i) {
        row_ptr[i] = run;
        run += cnt[i];
    }
    if (t == 1023) row_ptr[NN] = run;  // == EE
}

__global__ __launch_bounds__(256) void k_scatter(const int* __restrict__ src,
                                                 const int* __restrict__ dst,
                                                 const int* __restrict__ row_ptr,
                                                 int* __restrict__ fill,
                                                 int* __restrict__ esrc) {
    int e = blockIdx.x * 256 + threadIdx.x;
    if (e >= EE) return;
    int d = dst[e];
    int pos = row_ptr[d] + atomicAdd(&fill[d], 1);
    esrc[pos] = src[e];
}

// ---------------- GEMM 64x64 tile (layer 2: Ncols=64) ----------------

__global__ __launch_bounds__(256) void k_gemm(const float* __restrict__ A,
                                              const float* __restrict__ B,
                                              float* __restrict__ C,
                                              int Mrows, int Ncols) {
    const int K = 256;
    __shared__ float As[16][64];  // [k][m]
    __shared__ float Bs[16][64];  // [k][n]
    int tid = threadIdx.x;
    int tx = tid & 15;  // n
    int ty = tid >> 4;  // m
    int row0 = blockIdx.x * 64;
    int col0 = blockIdx.y * 64;
    int lam = tid >> 2;         // 0..63 row in A tile
    int lak = (tid & 3) * 4;    // k offset
    int lbk = tid >> 4;         // 0..15 k row in B tile
    int lbn = (tid & 15) * 4;   // n offset
    float acc[4][4] = {};
    for (int k0 = 0; k0 < K; k0 += 16) {
        float4 av = {0.f, 0.f, 0.f, 0.f};
        int ar = row0 + lam;
        if (ar < Mrows) av = *(const float4*)(A + (size_t)ar * K + k0 + lak);
        As[lak + 0][lam] = av.x;
        As[lak + 1][lam] = av.y;
        As[lak + 2][lam] = av.z;
        As[lak + 3][lam] = av.w;
        float4 bv = *(const float4*)(B + (size_t)(k0 + lbk) * Ncols + col0 + lbn);
        *(float4*)&Bs[lbk][lbn] = bv;
        __syncthreads();
#pragma unroll
        for (int k = 0; k < 16; ++k) {
            float4 ra = *(const float4*)&As[k][ty * 4];
            float4 rb = *(const float4*)&Bs[k][tx * 4];
            float a4[4] = {ra.x, ra.y, ra.z, ra.w};
            float b4[4] = {rb.x, rb.y, rb.z, rb.w};
#pragma unroll
            for (int um = 0; um < 4; ++um)
#pragma unroll
                for (int un = 0; un < 4; ++un) acc[um][un] += a4[um] * b4[un];
        }
        __syncthreads();
    }
#pragma unroll
    for (int um = 0; um < 4; ++um) {
        int r = row0 + ty * 4 + um;
        if (r < Mrows) {
            float4 v = {acc[um][0], acc[um][1], acc[um][2], acc[um][3]};
            *(float4*)(C + (size_t)r * Ncols + col0 + tx * 4) = v;
        }
    }
}

// ---------------- GEMM 128x128 tile, 8x8 micro (layer 1: Ncols=256) --------

__global__ __launch_bounds__(256) void k_gemm128(const float* __restrict__ A,
                                                 const float* __restrict__ B,
                                                 float* __restrict__ C,
                                                 int Mrows, int Ncols) {
    const int K = 256;
    __shared__ float As[16][128];
    __shared__ float Bs[16][128];
    int tid = threadIdx.x;
    int tx = tid & 15;   // n quad
    int ty = tid >> 4;   // m quad
    int row0 = blockIdx.x * 128;
    int col0 = blockIdx.y * 128;
    int lam = tid >> 1;          // 0..127 (row of A tile)
    int lak = (tid & 1) * 8;     // 0 or 8 (k offset, 8 floats)
    int lbk = tid >> 4;          // 0..15 (k row of B tile)
    int lbn = (tid & 15) * 8;    // 0..120 (col offset, 8 floats)
    float acc[2][2][4][4] = {};
    for (int k0 = 0; k0 < K; k0 += 16) {
        int ar = row0 + lam;
        float4 av0 = {0.f, 0.f, 0.f, 0.f}, av1 = {0.f, 0.f, 0.f, 0.f};
        if (ar < Mrows) {
            const float* ap = A + (size_t)ar * K + k0 + lak;
            av0 = *(const float4*)(ap);
            av1 = *(const float4*)(ap + 4);
        }
        As[lak + 0][lam] = av0.x;
        As[lak + 1][lam] = av0.y;
        As[lak + 2][lam] = av0.z;
        As[lak + 3][lam] = av0.w;
        As[lak + 4][lam] = av1.x;
        As[lak + 5][lam] = av1.y;
        As[lak + 6][lam] = av1.z;
        As[lak + 7][lam] = av1.w;
        const float* bp = B + (size_t)(k0 + lbk) * Ncols + col0 + lbn;
        *(float4*)&Bs[lbk][lbn] = *(const float4*)(bp);
        *(float4*)&Bs[lbk][lbn + 4] = *(const float4*)(bp + 4);
        __syncthreads();
#pragma unroll
        for (int k = 0; k < 16; ++k) {
            float4 a0 = *(const float4*)&As[k][ty * 4];
            float4 a1 = *(const float4*)&As[k][ty * 4 + 64];
            float4 b0 = *(const float4*)&Bs[k][tx * 4];
            float4 b1 = *(const float4*)&Bs[k][tx * 4 + 64];
            float am[2][4] = {{a0.x, a0.y, a0.z, a0.w}, {a1.x, a1.y, a1.z, a1.w}};
            float bn[2][4] = {{b0.x, b0.y, b0.z, b0.w}, {b1.x, b1.y, b1.z, b1.w}};
#pragma unroll
            for (int im = 0; im < 2; ++im)
#pragma unroll
                for (int jn = 0; jn < 2; ++jn)
#pragma unroll
                    for (int um = 0; um < 4; ++um)
#pragma unroll
                        for (int un = 0; un < 4; ++un)
                            acc[im][jn][um][un] += am[im][um] * bn[jn][un];
        }
        __syncthreads();
    }
#pragma unroll
    for (int im = 0; im < 2; ++im)
#pragma unroll
        for (int um = 0; um < 4; ++um) {
            int r = row0 + im * 64 + ty * 4 + um;
            if (r < Mrows) {
#pragma unroll
                for (int jn = 0; jn < 2; ++jn) {
                    float4 v = {acc[im][jn][um][0], acc[im][jn][um][1],
                                acc[im][jn][um][2], acc[im][jn][um][3]};
                    *(float4*)(C + (size_t)r * Ncols + col0 + jn * 64 + tx * 4) = v;
                }
            }
        }
}

// ---------------- el/er: per (node, head) dot with al/ar ----------------

template <int H, int D>
__global__ __launch_bounds__(256) void k_el_er(const float* __restrict__ feat,
                                               const float* __restrict__ al,
                                               const float* __restrict__ ar,
                                               float* __restrict__ el,
                                               float* __restrict__ er) {
    int idx = blockIdx.x * 256 + threadIdx.x;
    if (idx >= NN * H) return;
    int i = idx / H, hh = idx % H;
    const float* fp = feat + (size_t)i * (H * D) + hh * D;
    float sl = 0.f, sr = 0.f;
#pragma unroll
    for (int d = 0; d < D; d += 4) {
        float4 v = *(const float4*)(fp + d);
        sl += v.x * al[hh * D + d] + v.y * al[hh * D + d + 1] +
              v.z * al[hh * D + d + 2] + v.w * al[hh * D + d + 3];
        sr += v.x * ar[hh * D + d] + v.y * ar[hh * D + d + 1] +
              v.z * ar[hh * D + d + 2] + v.w * ar[hh * D + d + 3];
    }
    el[idx] = sl;
    er[idx] = sr;
}

// ---------------- layer-1 fused online-softmax aggregation ----------------
// one wave per dst node; lane l owns channels 4l..4l+3 (head = l>>3).
// chunk-8 software pipeline: 8 esrc, 8 el gathers, one rescale, 8 feat
// float4 gathers all independent -> high memory-level parallelism.
// NaN-safety: every chunk starts at a real edge (j0<hi), so m is finite
// after chunk 1 and padded slots give exp(-inf - finite) = 0.

#define CH1 8

__global__ __launch_bounds__(256) void k_agg1(const float* __restrict__ feat,
                                              const float* __restrict__ el,
                                              const float* __restrict__ er,
                                              const int* __restrict__ rp,
                                              const int* __restrict__ esrc,
                                              const float* __restrict__ bias,
                                              float* __restrict__ out) {
    int wid = threadIdx.x >> 6;
    int lane = threadIdx.x & 63;
    int i = blockIdx.x * 4 + wid;
    if (i >= NN) return;
    int hh = lane >> 3;
    float er_i = er[i * 8 + hh];
    int lo = rp[i], hi = rp[i + 1];
    float m = -INFINITY, s = 0.f;
    float4 acc = {0.f, 0.f, 0.f, 0.f};
    for (int j0 = lo; j0 < hi; j0 += CH1) {
        int sn[CH1];
        float x[CH1];
        sn[0] = esrc[j0];
#pragma unroll
        for (int t = 1; t < CH1; ++t) sn[t] = (j0 + t < hi) ? esrc[j0 + t] : sn[0];
#pragma unroll
        for (int t = 0; t < CH1; ++t) {
            float v = el[sn[t] * 8 + hh] + er_i;
            v = (v >= 0.f) ? v : NEG_SLOPE * v;
            x[t] = (j0 + t < hi) ? v : -INFINITY;
        }
        float M = x[0];
#pragma unroll
        for (int t = 1; t < CH1; ++t) M = fmaxf(M, x[t]);
        if (M > m) {
            float r = __expf(m - M);  // first chunk: exp(-inf)=0
            s *= r;
            acc.x *= r; acc.y *= r; acc.z *= r; acc.w *= r;
            m = M;
        }
        float w[CH1];
#pragma unroll
        for (int t = 0; t < CH1; ++t) {
            w[t] = __expf(x[t] - m);  // guarded slots: exp(-inf)=0
            s += w[t];
        }
        float4 f[CH1];
#pragma unroll
        for (int t = 0; t < CH1; ++t)
            f[t] = *(const float4*)(feat + (size_t)sn[t] * 256 + lane * 4);
#pragma unroll
        for (int t = 0; t < CH1; ++t) {
            acc.x += f[t].x * w[t];
            acc.y += f[t].y * w[t];
            acc.z += f[t].z * w[t];
            acc.w += f[t].w * w[t];
        }
    }
    float inv = 1.f / s;
    const float4 b = *(const float4*)(bias + lane * 4);
    float4 v = {acc.x * inv + b.x, acc.y * inv + b.y,
                acc.z * inv + b.z, acc.w * inv + b.w};
    v.x = (v.x > 0.f) ? v.x : (__expf(v.x) - 1.f);
    v.y = (v.y > 0.f) ? v.y : (__expf(v.y) - 1.f);
    v.z = (v.z > 0.f) ? v.z : (__expf(v.z) - 1.f);
    v.w = (v.w > 0.f) ? v.w : (__expf(v.w) - 1.f);
    *(float4*)(out + (size_t)i * 256 + lane * 4) = v;
}

// ---------------- layer-2 fused online-softmax aggregation ----------------
// one wave per dst node; 4 edge-groups of 16 lanes; chunk-2 per group.
// NaN fix (R7): a group with zero real edges keeps m = -inf; computing
// exp(xa - m) there is exp(-inf - -inf) = NaN. Force w = 0 for padded
// slots so empty groups carry (m,s,acc) = (-inf, 0, 0), which the
// -inf-guarded merge combines as exact zeros.

__global__ __launch_bounds__(256) void k_agg2(const float* __restrict__ feat2,
                                              const float* __restrict__ el2,
                                              const float* __restrict__ er2,
                                              const int* __restrict__ rp,
                                              const int* __restrict__ esrc,
                                              const float* __restrict__ b2,
                                              float* __restrict__ out) {
    int wid = threadIdx.x >> 6;
    int lane = threadIdx.x & 63;
    int i = blockIdx.x * 4 + wid;
    if (i >= NN) return;
    int g = lane >> 4;   // edge group 0..3
    int c = lane & 15;   // channel quad
    int lo = rp[i], hi = rp[i + 1];
    float er_i = er2[i];
    int sn_safe = esrc[lo];
    float m = -INFINITY, s = 0.f;
    float4 acc = {0.f, 0.f, 0.f, 0.f};
    for (int j0 = lo; j0 < hi; j0 += 8) {
        int ja = j0 + g, jb = j0 + 4 + g;
        int sna = (ja < hi) ? esrc[ja] : sn_safe;
        int snb = (jb < hi) ? esrc[jb] : sn_safe;
        float xa = el2[sna] + er_i;
        float xb = el2[snb] + er_i;
        xa = (xa >= 0.f) ? xa : NEG_SLOPE * xa;
        xb = (xb >= 0.f) ? xb : NEG_SLOPE * xb;
        if (ja >= hi) xa = -INFINITY;
        if (jb >= hi) xb = -INFINITY;
        float M = fmaxf(xa, xb);
        if (M > m) {
            float r = __expf(m - M);
            s *= r;
            acc.x *= r; acc.y *= r; acc.z *= r; acc.w *= r;
            m = M;
        }
        float wa = (ja < hi) ? __expf(xa - m) : 0.f;  // NaN fix: empty group m=-inf
        float wb = (jb < hi) ? __expf(xb - m) : 0.f;
        s += wa + wb;
        const float4 fa = *(const float4*)(feat2 + (size_t)sna * 64 + c * 4);
        const float4 fb = *(const float4*)(feat2 + (size_t)snb * 64 + c * 4);
        acc.x += fa.x * wa + fb.x * wb;
        acc.y += fa.y * wa + fb.y * wb;
        acc.z += fa.z * wa + fb.z * wb;
        acc.w += fa.w * wa + fb.w * wb;
    }
    // merge (m, s, acc) across the 4 groups
#pragma unroll
    for (int off = 16; off < 64; off <<= 1) {
        float mo = __shfl_xor(m, off);
        float so = __shfl_xor(s, off);
        float4 ao;
        ao.x = __shfl_xor(acc.x, off);
        ao.y = __shfl_xor(acc.y, off);
        ao.z = __shfl_xor(acc.z, off);
        ao.w = __shfl_xor(acc.w, off);
        float M = fmaxf(m, mo);
        float w0 = (m == -INFINITY) ? 0.f : __expf(m - M);
        float w1 = (mo == -INFINITY) ? 0.f : __expf(mo - M);
        s = s * w0 + so * w1;
        acc.x = acc.x * w0 + ao.x * w1;
        acc.y = acc.y * w0 + ao.y * w1;
        acc.z = acc.z * w0 + ao.z * w1;
        acc.w = acc.w * w0 + ao.w * w1;
        m = M;
    }
    if (g == 0) {
        float inv = 1.f / s;
        const float4 b = *(const float4*)(b2 + c * 4);
        float4 v = {acc.x * inv + b.x, acc.y * inv + b.y,
                    acc.z * inv + b.z, acc.w * inv + b.w};
        *(float4*)(out + (size_t)i * 64 + c * 4) = v;
    }
}

// ---------------- launch ----------------

extern "C" void kernel_launch(void* const* d_in, const int* in_sizes, int n_in,
                              void* d_out, int out_size, void* d_ws, size_t ws_size,
                              hipStream_t stream) {
    const float* h   = (const float*)d_in[0];
    const float* W1  = (const float*)d_in[1];
    const float* al1 = (const float*)d_in[2];
    const float* ar1 = (const float*)d_in[3];
    const float* b1  = (const float*)d_in[4];
    const float* W2  = (const float*)d_in[5];
    const float* al2 = (const float*)d_in[6];
    const float* ar2 = (const float*)d_in[7];
    const float* b2  = (const float*)d_in[8];
    const int* src   = (const int*)d_in[9];
    const int* dst   = (const int*)d_in[10];
    float* out = (float*)d_out;

    // workspace carve
    float* fp = (float*)d_ws;
    float* feat1 = fp; fp += (size_t)NN * 256;   // feat2 aliases feat1 (dead after k_agg1)
    float* h1    = fp; fp += (size_t)NN * 256;
    float* el1 = fp; fp += (size_t)NN * 8;
    float* er1 = fp; fp += (size_t)NN * 8;
    float* el2 = fp; fp += NN;
    float* er2 = fp; fp += NN;
    float* feat2 = feat1;
    int* ip = (int*)fp;
    int* row_ptr = ip; ip += NN + 1;
    int* cnt  = ip; ip += NN;
    int* fill = ip; ip += NN;   // adjacent to cnt: single memset covers both
    int* esrc = ip; ip += EE;

    hipMemsetAsync(cnt, 0, sizeof(int) * 2 * NN, stream);

    // CSR by dst
    k_hist<<<(EE + 255) / 256, 256, 0, stream>>>(dst, cnt);
    k_scan<<<1, 1024, 0, stream>>>(cnt, row_ptr);
    k_scatter<<<(EE + 255) / 256, 256, 0, stream>>>(src, dst, row_ptr, fill, esrc);

    // layer 1
    dim3 g1((NN + 127) / 128, 256 / 128);
    k_gemm128<<<g1, 256, 0, stream>>>(h, W1, feat1, NN, 256);
    k_el_er<8, 32><<<(NN * 8 + 255) / 256, 256, 0, stream>>>(feat1, al1, ar1, el1, er1);
    k_agg1<<<(NN + 3) / 4, 256, 0, stream>>>(feat1, el1, er1, row_ptr, esrc, b1, h1);

    // layer 2
    dim3 g2((NN + 63) / 64, 64 / 64);
    k_gemm<<<g2, 256, 0, stream>>>(h1, W2, feat2, NN, 64);
    k_el_er<1, 64><<<(NN + 255) / 256, 256, 0, stream>>>(feat2, al2, ar2, el2, er2);
    k_agg2<<<(NN + 3) / 4, 256, 0, stream>>>(feat2, el2, er2, row_ptr, esrc, b2, out);
}

// Round 10
// 523.352 us; speedup vs baseline: 1.2402x; 1.0981x over previous
//
#include <hip/hip_runtime.h>
#include <math.h>

#define NN 50000
#define EE 850000
#define IN_DIM 256
#define HID 32
#define H1 8
#define OUT_DIM 64
#define NEG_SLOPE 0.2f

// bf16 helpers: RNE pack, and cheap unpack from a uint holding 2 bf16
__device__ __forceinline__ unsigned short f2bf(float x) {
    unsigned int u = __float_as_uint(x);
    u += 0x7fffu + ((u >> 16) & 1u);
    return (unsigned short)(u >> 16);
}
__device__ __forceinline__ float bflo(unsigned int p) { return __uint_as_float(p << 16); }
__device__ __forceinline__ float bfhi(unsigned int p) { return __uint_as_float(p & 0xffff0000u); }

// ---------------- CSR build ----------------

__global__ __launch_bounds__(256) void k_hist(const int* __restrict__ dst,
                                              int* __restrict__ cnt) {
    int e = blockIdx.x * 256 + threadIdx.x;
    if (e < EE) atomicAdd(&cnt[dst[e]], 1);
}

// single-block exclusive scan over N counts -> row_ptr[N+1]
__global__ __launch_bounds__(1024) void k_scan(const int* __restrict__ cnt,
                                               int* __restrict__ row_ptr) {
    __shared__ int sums[1024];
    int t = threadIdx.x;
    const int CH = (NN + 1023) / 1024;  // 49
    int lo = t * CH, hi = lo + CH;
    if (lo > NN) lo = NN;
    if (hi > NN) hi = NN;
    int s = 0;
    for (int i = lo; i < hi; ++i) s += cnt[i];
    sums[t] = s;
    __syncthreads();
    for (int off = 1; off < 1024; off <<= 1) {
        int v = (t >= off) ? sums[t - off] : 0;
        __syncthreads();
        sums[t] += v;
        __syncthreads();
    }
    int run = (t > 0) ? sums[t - 1] : 0;
    for (int i = lo; i < hi; ++i) {
        row_ptr[i] = run;
        run += cnt[i];
    }
    if (t == 1023) row_ptr[NN] = run;  // == EE
}

__global__ __launch_bounds__(256) void k_scatter(const int* __restrict__ src,
                                                 const int* __restrict__ dst,
                                                 const int* __restrict__ row_ptr,
                                                 int* __restrict__ fill,
                                                 int* __restrict__ esrc) {
    int e = blockIdx.x * 256 + threadIdx.x;
    if (e >= EE) return;
    int d = dst[e];
    int pos = row_ptr[d] + atomicAdd(&fill[d], 1);
    esrc[pos] = src[e];
}

// ---------------- GEMM 64x64 tile (layer 2), bf16 output ----------------

__global__ __launch_bounds__(256) void k_gemm(const float* __restrict__ A,
                                              const float* __restrict__ B,
                                              unsigned short* __restrict__ C,
                                              int Mrows, int Ncols) {
    const int K = 256;
    __shared__ float As[16][64];  // [k][m]
    __shared__ float Bs[16][64];  // [k][n]
    int tid = threadIdx.x;
    int tx = tid & 15;  // n
    int ty = tid >> 4;  // m
    int row0 = blockIdx.x * 64;
    int col0 = blockIdx.y * 64;
    int lam = tid >> 2;         // 0..63 row in A tile
    int lak = (tid & 3) * 4;    // k offset
    int lbk = tid >> 4;         // 0..15 k row in B tile
    int lbn = (tid & 15) * 4;   // n offset
    float acc[4][4] = {};
    for (int k0 = 0; k0 < K; k0 += 16) {
        float4 av = {0.f, 0.f, 0.f, 0.f};
        int ar = row0 + lam;
        if (ar < Mrows) av = *(const float4*)(A + (size_t)ar * K + k0 + lak);
        As[lak + 0][lam] = av.x;
        As[lak + 1][lam] = av.y;
        As[lak + 2][lam] = av.z;
        As[lak + 3][lam] = av.w;
        float4 bv = *(const float4*)(B + (size_t)(k0 + lbk) * Ncols + col0 + lbn);
        *(float4*)&Bs[lbk][lbn] = bv;
        __syncthreads();
#pragma unroll
        for (int k = 0; k < 16; ++k) {
            float4 ra = *(const float4*)&As[k][ty * 4];
            float4 rb = *(const float4*)&Bs[k][tx * 4];
            float a4[4] = {ra.x, ra.y, ra.z, ra.w};
            float b4[4] = {rb.x, rb.y, rb.z, rb.w};
#pragma unroll
            for (int um = 0; um < 4; ++um)
#pragma unroll
                for (int un = 0; un < 4; ++un) acc[um][un] += a4[um] * b4[un];
        }
        __syncthreads();
    }
#pragma unroll
    for (int um = 0; um < 4; ++um) {
        int r = row0 + ty * 4 + um;
        if (r < Mrows) {
            ushort4 v = {f2bf(acc[um][0]), f2bf(acc[um][1]),
                         f2bf(acc[um][2]), f2bf(acc[um][3])};
            *(ushort4*)(C + (size_t)r * Ncols + col0 + tx * 4) = v;
        }
    }
}

// ---------------- GEMM 128x128 tile, 8x8 micro (layer 1), bf16 output ------

__global__ __launch_bounds__(256) void k_gemm128(const float* __restrict__ A,
                                                 const float* __restrict__ B,
                                                 unsigned short* __restrict__ C,
                                                 int Mrows, int Ncols) {
    const int K = 256;
    __shared__ float As[16][128];
    __shared__ float Bs[16][128];
    int tid = threadIdx.x;
    int tx = tid & 15;   // n quad
    int ty = tid >> 4;   // m quad
    int row0 = blockIdx.x * 128;
    int col0 = blockIdx.y * 128;
    int lam = tid >> 1;          // 0..127 (row of A tile)
    int lak = (tid & 1) * 8;     // 0 or 8 (k offset, 8 floats)
    int lbk = tid >> 4;          // 0..15 (k row of B tile)
    int lbn = (tid & 15) * 8;    // 0..120 (col offset, 8 floats)
    float acc[2][2][4][4] = {};
    for (int k0 = 0; k0 < K; k0 += 16) {
        int ar = row0 + lam;
        float4 av0 = {0.f, 0.f, 0.f, 0.f}, av1 = {0.f, 0.f, 0.f, 0.f};
        if (ar < Mrows) {
            const float* ap = A + (size_t)ar * K + k0 + lak;
            av0 = *(const float4*)(ap);
            av1 = *(const float4*)(ap + 4);
        }
        As[lak + 0][lam] = av0.x;
        As[lak + 1][lam] = av0.y;
        As[lak + 2][lam] = av0.z;
        As[lak + 3][lam] = av0.w;
        As[lak + 4][lam] = av1.x;
        As[lak + 5][lam] = av1.y;
        As[lak + 6][lam] = av1.z;
        As[lak + 7][lam] = av1.w;
        const float* bp = B + (size_t)(k0 + lbk) * Ncols + col0 + lbn;
        *(float4*)&Bs[lbk][lbn] = *(const float4*)(bp);
        *(float4*)&Bs[lbk][lbn + 4] = *(const float4*)(bp + 4);
        __syncthreads();
#pragma unroll
        for (int k = 0; k < 16; ++k) {
            float4 a0 = *(const float4*)&As[k][ty * 4];
            float4 a1 = *(const float4*)&As[k][ty * 4 + 64];
            float4 b0 = *(const float4*)&Bs[k][tx * 4];
            float4 b1 = *(const float4*)&Bs[k][tx * 4 + 64];
            float am[2][4] = {{a0.x, a0.y, a0.z, a0.w}, {a1.x, a1.y, a1.z, a1.w}};
            float bn[2][4] = {{b0.x, b0.y, b0.z, b0.w}, {b1.x, b1.y, b1.z, b1.w}};
#pragma unroll
            for (int im = 0; im < 2; ++im)
#pragma unroll
                for (int jn = 0; jn < 2; ++jn)
#pragma unroll
                    for (int um = 0; um < 4; ++um)
#pragma unroll
                        for (int un = 0; un < 4; ++un)
                            acc[im][jn][um][un] += am[im][um] * bn[jn][un];
        }
        __syncthreads();
    }
#pragma unroll
    for (int im = 0; im < 2; ++im)
#pragma unroll
        for (int um = 0; um < 4; ++um) {
            int r = row0 + im * 64 + ty * 4 + um;
            if (r < Mrows) {
#pragma unroll
                for (int jn = 0; jn < 2; ++jn) {
                    ushort4 v = {f2bf(acc[im][jn][um][0]), f2bf(acc[im][jn][um][1]),
                                 f2bf(acc[im][jn][um][2]), f2bf(acc[im][jn][um][3])};
                    *(ushort4*)(C + (size_t)r * Ncols + col0 + jn * 64 + tx * 4) = v;
                }
            }
        }
}

// ---------------- el/er from bf16 feat ----------------

template <int H, int D>
__global__ __launch_bounds__(256) void k_el_er(const unsigned short* __restrict__ feat,
                                               const float* __restrict__ al,
                                               const float* __restrict__ ar,
                                               float* __restrict__ el,
                                               float* __restrict__ er) {
    int idx = blockIdx.x * 256 + threadIdx.x;
    if (idx >= NN * H) return;
    int i = idx / H, hh = idx % H;
    const uint4* fp = reinterpret_cast<const uint4*>(feat + (size_t)i * (H * D) + hh * D);
    float sl = 0.f, sr = 0.f;
#pragma unroll
    for (int d8 = 0; d8 < D / 8; ++d8) {
        uint4 q = fp[d8];
        float f[8] = {bflo(q.x), bfhi(q.x), bflo(q.y), bfhi(q.y),
                      bflo(q.z), bfhi(q.z), bflo(q.w), bfhi(q.w)};
        int d = d8 * 8;
#pragma unroll
        for (int t = 0; t < 8; ++t) {
            sl += f[t] * al[hh * D + d + t];
            sr += f[t] * ar[hh * D + d + t];
        }
    }
    el[idx] = sl;
    er[idx] = sr;
}

// ---------------- layer-1 fused online-softmax aggregation ----------------
// one wave per dst node; lane l owns channels 4l..4l+3 (head = l>>3).
// chunk-8 pipeline; feat gathered as bf16 (8 B/lane, 512 B/wave/edge).

#define CH1 8

__global__ __launch_bounds__(256) void k_agg1(const unsigned short* __restrict__ feat,
                                              const float* __restrict__ el,
                                              const float* __restrict__ er,
                                              const int* __restrict__ rp,
                                              const int* __restrict__ esrc,
                                              const float* __restrict__ bias,
                                              float* __restrict__ out) {
    int wid = threadIdx.x >> 6;
    int lane = threadIdx.x & 63;
    int i = blockIdx.x * 4 + wid;
    if (i >= NN) return;
    int hh = lane >> 3;
    float er_i = er[i * 8 + hh];
    int lo = rp[i], hi = rp[i + 1];
    float m = -INFINITY, s = 0.f;
    float4 acc = {0.f, 0.f, 0.f, 0.f};
    for (int j0 = lo; j0 < hi; j0 += CH1) {
        int sn[CH1];
        float x[CH1];
        sn[0] = esrc[j0];
#pragma unroll
        for (int t = 1; t < CH1; ++t) sn[t] = (j0 + t < hi) ? esrc[j0 + t] : sn[0];
#pragma unroll
        for (int t = 0; t < CH1; ++t) {
            float v = el[sn[t] * 8 + hh] + er_i;
            v = (v >= 0.f) ? v : NEG_SLOPE * v;
            x[t] = (j0 + t < hi) ? v : -INFINITY;
        }
        float M = x[0];
#pragma unroll
        for (int t = 1; t < CH1; ++t) M = fmaxf(M, x[t]);
        if (M > m) {
            float r = __expf(m - M);  // first chunk: exp(-inf)=0
            s *= r;
            acc.x *= r; acc.y *= r; acc.z *= r; acc.w *= r;
            m = M;
        }
        float w[CH1];
#pragma unroll
        for (int t = 0; t < CH1; ++t) {
            w[t] = __expf(x[t] - m);  // guarded slots: exp(-inf)=0
            s += w[t];
        }
        uint2 f[CH1];
#pragma unroll
        for (int t = 0; t < CH1; ++t)
            f[t] = *(const uint2*)(feat + (size_t)sn[t] * 256 + lane * 4);
#pragma unroll
        for (int t = 0; t < CH1; ++t) {
            acc.x += bflo(f[t].x) * w[t];
            acc.y += bfhi(f[t].x) * w[t];
            acc.z += bflo(f[t].y) * w[t];
            acc.w += bfhi(f[t].y) * w[t];
        }
    }
    float inv = 1.f / s;
    const float4 b = *(const float4*)(bias + lane * 4);
    float4 v = {acc.x * inv + b.x, acc.y * inv + b.y,
                acc.z * inv + b.z, acc.w * inv + b.w};
    v.x = (v.x > 0.f) ? v.x : (__expf(v.x) - 1.f);
    v.y = (v.y > 0.f) ? v.y : (__expf(v.y) - 1.f);
    v.z = (v.z > 0.f) ? v.z : (__expf(v.z) - 1.f);
    v.w = (v.w > 0.f) ? v.w : (__expf(v.w) - 1.f);
    *(float4*)(out + (size_t)i * 256 + lane * 4) = v;
}

// ---------------- layer-2 fused online-softmax aggregation ----------------
// one wave per dst node; 4 edge-groups of 16 lanes; bf16 feat2 gathers.
// padded slots forced to w=0 (empty group keeps m=-inf; merge is guarded).

__global__ __launch_bounds__(256) void k_agg2(const unsigned short* __restrict__ feat2,
                                              const float* __restrict__ el2,
                                              const float* __restrict__ er2,
                                              const int* __restrict__ rp,
                                              const int* __restrict__ esrc,
                                              const float* __restrict__ b2,
                                              float* __restrict__ out) {
    int wid = threadIdx.x >> 6;
    int lane = threadIdx.x & 63;
    int i = blockIdx.x * 4 + wid;
    if (i >= NN) return;
    int g = lane >> 4;   // edge group 0..3
    int c = lane & 15;   // channel quad
    int lo = rp[i], hi = rp[i + 1];
    float er_i = er2[i];
    int sn_safe = esrc[lo];
    float m = -INFINITY, s = 0.f;
    float4 acc = {0.f, 0.f, 0.f, 0.f};
    for (int j0 = lo; j0 < hi; j0 += 8) {
        int ja = j0 + g, jb = j0 + 4 + g;
        int sna = (ja < hi) ? esrc[ja] : sn_safe;
        int snb = (jb < hi) ? esrc[jb] : sn_safe;
        float xa = el2[sna] + er_i;
        float xb = el2[snb] + er_i;
        xa = (xa >= 0.f) ? xa : NEG_SLOPE * xa;
        xb = (xb >= 0.f) ? xb : NEG_SLOPE * xb;
        if (ja >= hi) xa = -INFINITY;
        if (jb >= hi) xb = -INFINITY;
        float M = fmaxf(xa, xb);
        if (M > m) {
            float r = __expf(m - M);
            s *= r;
            acc.x *= r; acc.y *= r; acc.z *= r; acc.w *= r;
            m = M;
        }
        float wa = (ja < hi) ? __expf(xa - m) : 0.f;  // NaN guard: empty group m=-inf
        float wb = (jb < hi) ? __expf(xb - m) : 0.f;
        s += wa + wb;
        const uint2 fa = *(const uint2*)(feat2 + (size_t)sna * 64 + c * 4);
        const uint2 fb = *(const uint2*)(feat2 + (size_t)snb * 64 + c * 4);
        acc.x += bflo(fa.x) * wa + bflo(fb.x) * wb;
        acc.y += bfhi(fa.x) * wa + bfhi(fb.x) * wb;
        acc.z += bflo(fa.y) * wa + bflo(fb.y) * wb;
        acc.w += bfhi(fa.y) * wa + bfhi(fb.y) * wb;
    }
    // merge (m, s, acc) across the 4 groups
#pragma unroll
    for (int off = 16; off < 64; off <<= 1) {
        float mo = __shfl_xor(m, off);
        float so = __shfl_xor(s, off);
        float4 ao;
        ao.x = __shfl_xor(acc.x, off);
        ao.y = __shfl_xor(acc.y, off);
        ao.z = __shfl_xor(acc.z, off);
        ao.w = __shfl_xor(acc.w, off);
        float M = fmaxf(m, mo);
        float w0 = (m == -INFINITY) ? 0.f : __expf(m - M);
        float w1 = (mo == -INFINITY) ? 0.f : __expf(mo - M);
        s = s * w0 + so * w1;
        acc.x = acc.x * w0 + ao.x * w1;
        acc.y = acc.y * w0 + ao.y * w1;
        acc.z = acc.z * w0 + ao.z * w1;
        acc.w = acc.w * w0 + ao.w * w1;
        m = M;
    }
    if (g == 0) {
        float inv = 1.f / s;
        const float4 b = *(const float4*)(b2 + c * 4);
        float4 v = {acc.x * inv + b.x, acc.y * inv + b.y,
                    acc.z * inv + b.z, acc.w * inv + b.w};
        *(float4*)(out + (size_t)i * 64 + c * 4) = v;
    }
}

// ---------------- launch ----------------

extern "C" void kernel_launch(void* const* d_in, const int* in_sizes, int n_in,
                              void* d_out, int out_size, void* d_ws, size_t ws_size,
                              hipStream_t stream) {
    const float* h   = (const float*)d_in[0];
    const float* W1  = (const float*)d_in[1];
    const float* al1 = (const float*)d_in[2];
    const float* ar1 = (const float*)d_in[3];
    const float* b1  = (const float*)d_in[4];
    const float* W2  = (const float*)d_in[5];
    const float* al2 = (const float*)d_in[6];
    const float* ar2 = (const float*)d_in[7];
    const float* b2  = (const float*)d_in[8];
    const int* src   = (const int*)d_in[9];
    const int* dst   = (const int*)d_in[10];
    float* out = (float*)d_out;

    // workspace carve (~84 MB)
    float* fp = (float*)d_ws;
    float* h1  = fp; fp += (size_t)NN * 256;
    float* el1 = fp; fp += (size_t)NN * 8;
    float* er1 = fp; fp += (size_t)NN * 8;
    float* el2 = fp; fp += NN;
    float* er2 = fp; fp += NN;
    unsigned short* feat1 = (unsigned short*)fp;           // NN*256 bf16
    unsigned short* feat2 = feat1;                          // aliases (feat1 dead after agg1)
    int* ip = (int*)(feat1 + (size_t)NN * 256);
    int* row_ptr = ip; ip += NN + 1;
    int* cnt  = ip; ip += NN;
    int* fill = ip; ip += NN;   // adjacent to cnt: single memset covers both
    int* esrc = ip; ip += EE;

    hipMemsetAsync(cnt, 0, sizeof(int) * 2 * NN, stream);

    // CSR by dst
    k_hist<<<(EE + 255) / 256, 256, 0, stream>>>(dst, cnt);
    k_scan<<<1, 1024, 0, stream>>>(cnt, row_ptr);
    k_scatter<<<(EE + 255) / 256, 256, 0, stream>>>(src, dst, row_ptr, fill, esrc);

    // layer 1
    dim3 g1((NN + 127) / 128, 256 / 128);
    k_gemm128<<<g1, 256, 0, stream>>>(h, W1, feat1, NN, 256);
    k_el_er<8, 32><<<(NN * 8 + 255) / 256, 256, 0, stream>>>(feat1, al1, ar1, el1, er1);
    k_agg1<<<(NN + 3) / 4, 256, 0, stream>>>(feat1, el1, er1, row_ptr, esrc, b1, h1);

    // layer 2
    dim3 g2((NN + 63) / 64, 64 / 64);
    k_gemm<<<g2, 256, 0, stream>>>(h1, W2, feat2, NN, 64);
    k_el_er<1, 64><<<(NN + 255) / 256, 256, 0, stream>>>(feat2, al2, ar2, el2, er2);
    k_agg2<<<(NN + 3) / 4, 256, 0, stream>>>(feat2, el2, er2, row_ptr, esrc, b2, out);
}

// Round 11
// 448.718 us; speedup vs baseline: 1.4464x; 1.1663x over previous
//
#include <hip/hip_runtime.h>
#include <math.h>

#define NN 50000
#define EE 850000
#define IN_DIM 256
#define HID 32
#define H1 8
#define OUT_DIM 64
#define NEG_SLOPE 0.2f

typedef short bf16x8 __attribute__((ext_vector_type(8)));
typedef float f32x4 __attribute__((ext_vector_type(4)));

// bf16 helpers: RNE pack, and cheap unpack from a uint holding 2 bf16
__device__ __forceinline__ unsigned short f2bf(float x) {
    unsigned int u = __float_as_uint(x);
    u += 0x7fffu + ((u >> 16) & 1u);
    return (unsigned short)(u >> 16);
}
__device__ __forceinline__ float bflo(unsigned int p) { return __uint_as_float(p << 16); }
__device__ __forceinline__ float bfhi(unsigned int p) { return __uint_as_float(p & 0xffff0000u); }

// ---------------- CSR build ----------------

__global__ __launch_bounds__(256) void k_hist(const int* __restrict__ dst,
                                              int* __restrict__ cnt) {
    int e = blockIdx.x * 256 + threadIdx.x;
    if (e < EE) atomicAdd(&cnt[dst[e]], 1);
}

__global__ __launch_bounds__(1024) void k_scan(const int* __restrict__ cnt,
                                               int* __restrict__ row_ptr) {
    __shared__ int sums[1024];
    int t = threadIdx.x;
    const int CH = (NN + 1023) / 1024;  // 49
    int lo = t * CH, hi = lo + CH;
    if (lo > NN) lo = NN;
    if (hi > NN) hi = NN;
    int s = 0;
    for (int i = lo; i < hi; ++i) s += cnt[i];
    sums[t] = s;
    __syncthreads();
    for (int off = 1; off < 1024; off <<= 1) {
        int v = (t >= off) ? sums[t - off] : 0;
        __syncthreads();
        sums[t] += v;
        __syncthreads();
    }
    int run = (t > 0) ? sums[t - 1] : 0;
    for (int i = lo; i < hi; ++i) {
        row_ptr[i] = run;
        run += cnt[i];
    }
    if (t == 1023) row_ptr[NN] = run;  // == EE
}

__global__ __launch_bounds__(256) void k_scatter(const int* __restrict__ src,
                                                 const int* __restrict__ dst,
                                                 const int* __restrict__ row_ptr,
                                                 int* __restrict__ fill,
                                                 int* __restrict__ esrc) {
    int e = blockIdx.x * 256 + threadIdx.x;
    if (e >= EE) return;
    int d = dst[e];
    int pos = row_ptr[d] + atomicAdd(&fill[d], 1);
    esrc[pos] = src[e];
}

// ---------------- W1 -> fragment-ordered bf16 image ----------------
// Fragment (ks, ct, lane): 8 bf16 = B[ks*32 + (lane>>4)*8 + j][ct*16 + (lane&15)],
// j ascending, pairs packed low-halfword-first. int4 slot index = ks*1024 + ct*64 + lane.

__global__ __launch_bounds__(256) void k_prepw(const float* __restrict__ W,
                                               unsigned int* __restrict__ Wf) {
    int t = blockIdx.x * 256 + threadIdx.x;  // 0..8191
    if (t >= 8 * 16 * 64) return;
    int lane = t & 63;
    int ct = (t >> 6) & 15;
    int ks = t >> 10;
    int col = ct * 16 + (lane & 15);
    int kbase = ks * 32 + (lane >> 4) * 8;
    uint4 o;
    unsigned int* ow = (unsigned int*)&o;
#pragma unroll
    for (int w = 0; w < 4; ++w) {
        unsigned int lo = f2bf(W[(size_t)(kbase + 2 * w) * 256 + col]);
        unsigned int hi = f2bf(W[(size_t)(kbase + 2 * w + 1) * 256 + col]);
        ow[w] = (hi << 16) | lo;
    }
    *(uint4*)(Wf + (size_t)t * 4) = o;
}

// ---------------- layer-1 GEMM via MFMA bf16 (f32 accum) ----------------
// one wave = 16 rows x 256 cols. A: in-register f32->bf16 from h.
// A frag: row=l&15, k=8*(l>>4)+j. B frag: direct 16B load from Wf.
// D: row=4*(l>>4)+i, col=ct*16+(l&15)  [m89-verified mapping].

__global__ __launch_bounds__(256) void k_mfma1(const float* __restrict__ A,
                                               const uint4* __restrict__ Wf,
                                               unsigned short* __restrict__ C) {
    int wave = (blockIdx.x * 256 + threadIdx.x) >> 6;
    int lane = threadIdx.x & 63;
    if (wave >= NN / 16) return;  // 3125 waves exactly
    int row0 = wave * 16;
    int arow = lane & 15, kg = lane >> 4;
    const float* ap = A + (size_t)(row0 + arow) * 256 + kg * 8;
    f32x4 acc[16];
#pragma unroll
    for (int t = 0; t < 16; ++t) acc[t] = (f32x4){0.f, 0.f, 0.f, 0.f};
#pragma unroll
    for (int ks = 0; ks < 8; ++ks) {
        float4 a0 = *(const float4*)(ap + ks * 32);
        float4 a1 = *(const float4*)(ap + ks * 32 + 4);
        union { bf16x8 v; unsigned int u[4]; } af;
        af.u[0] = ((unsigned)f2bf(a0.y) << 16) | f2bf(a0.x);
        af.u[1] = ((unsigned)f2bf(a0.w) << 16) | f2bf(a0.z);
        af.u[2] = ((unsigned)f2bf(a1.y) << 16) | f2bf(a1.x);
        af.u[3] = ((unsigned)f2bf(a1.w) << 16) | f2bf(a1.z);
        const uint4* wp = Wf + (size_t)ks * 1024 + lane;
#pragma unroll
        for (int ct = 0; ct < 16; ++ct) {
            union { uint4 i; bf16x8 v; } bf;
            bf.i = wp[ct * 64];
            acc[ct] = __builtin_amdgcn_mfma_f32_16x16x32_bf16(af.v, bf.v, acc[ct], 0, 0, 0);
        }
    }
    int orow0 = row0 + (lane >> 4) * 4;
    int ocol = lane & 15;
#pragma unroll
    for (int ct = 0; ct < 16; ++ct) {
#pragma unroll
        for (int i = 0; i < 4; ++i)
            C[(size_t)(orow0 + i) * 256 + ct * 16 + ocol] = f2bf(acc[ct][i]);
    }
}

// ---------------- GEMM 64x64 tile (layer 2), f32 in, bf16 out ----------------

__global__ __launch_bounds__(256) void k_gemm(const float* __restrict__ A,
                                              const float* __restrict__ B,
                                              unsigned short* __restrict__ C,
                                              int Mrows, int Ncols) {
    const int K = 256;
    __shared__ float As[16][64];  // [k][m]
    __shared__ float Bs[16][64];  // [k][n]
    int tid = threadIdx.x;
    int tx = tid & 15;  // n
    int ty = tid >> 4;  // m
    int row0 = blockIdx.x * 64;
    int col0 = blockIdx.y * 64;
    int lam = tid >> 2;         // 0..63 row in A tile
    int lak = (tid & 3) * 4;    // k offset
    int lbk = tid >> 4;         // 0..15 k row in B tile
    int lbn = (tid & 15) * 4;   // n offset
    float acc[4][4] = {};
    for (int k0 = 0; k0 < K; k0 += 16) {
        float4 av = {0.f, 0.f, 0.f, 0.f};
        int ar = row0 + lam;
        if (ar < Mrows) av = *(const float4*)(A + (size_t)ar * K + k0 + lak);
        As[lak + 0][lam] = av.x;
        As[lak + 1][lam] = av.y;
        As[lak + 2][lam] = av.z;
        As[lak + 3][lam] = av.w;
        float4 bv = *(const float4*)(B + (size_t)(k0 + lbk) * Ncols + col0 + lbn);
        *(float4*)&Bs[lbk][lbn] = bv;
        __syncthreads();
#pragma unroll
        for (int k = 0; k < 16; ++k) {
            float4 ra = *(const float4*)&As[k][ty * 4];
            float4 rb = *(const float4*)&Bs[k][tx * 4];
            float a4[4] = {ra.x, ra.y, ra.z, ra.w};
            float b4[4] = {rb.x, rb.y, rb.z, rb.w};
#pragma unroll
            for (int um = 0; um < 4; ++um)
#pragma unroll
                for (int un = 0; un < 4; ++un) acc[um][un] += a4[um] * b4[un];
        }
        __syncthreads();
    }
#pragma unroll
    for (int um = 0; um < 4; ++um) {
        int r = row0 + ty * 4 + um;
        if (r < Mrows) {
            ushort4 v = {f2bf(acc[um][0]), f2bf(acc[um][1]),
                         f2bf(acc[um][2]), f2bf(acc[um][3])};
            *(ushort4*)(C + (size_t)r * Ncols + col0 + tx * 4) = v;
        }
    }
}

// ---------------- el/er from bf16 feat ----------------

template <int H, int D>
__global__ __launch_bounds__(256) void k_el_er(const unsigned short* __restrict__ feat,
                                               const float* __restrict__ al,
                                               const float* __restrict__ ar,
                                               float* __restrict__ el,
                                               float* __restrict__ er) {
    int idx = blockIdx.x * 256 + threadIdx.x;
    if (idx >= NN * H) return;
    int i = idx / H, hh = idx % H;
    const uint4* fp = reinterpret_cast<const uint4*>(feat + (size_t)i * (H * D) + hh * D);
    float sl = 0.f, sr = 0.f;
#pragma unroll
    for (int d8 = 0; d8 < D / 8; ++d8) {
        uint4 q = fp[d8];
        float f[8] = {bflo(q.x), bfhi(q.x), bflo(q.y), bfhi(q.y),
                      bflo(q.z), bfhi(q.z), bflo(q.w), bfhi(q.w)};
        int d = d8 * 8;
#pragma unroll
        for (int t = 0; t < 8; ++t) {
            sl += f[t] * al[hh * D + d + t];
            sr += f[t] * ar[hh * D + d + t];
        }
    }
    el[idx] = sl;
    er[idx] = sr;
}

// ---------------- layer-1 fused online-softmax aggregation ----------------

#define CH1 8

__global__ __launch_bounds__(256) void k_agg1(const unsigned short* __restrict__ feat,
                                              const float* __restrict__ el,
                                              const float* __restrict__ er,
                                              const int* __restrict__ rp,
                                              const int* __restrict__ esrc,
                                              const float* __restrict__ bias,
                                              float* __restrict__ out) {
    int wid = threadIdx.x >> 6;
    int lane = threadIdx.x & 63;
    int i = blockIdx.x * 4 + wid;
    if (i >= NN) return;
    int hh = lane >> 3;
    float er_i = er[i * 8 + hh];
    int lo = rp[i], hi = rp[i + 1];
    float m = -INFINITY, s = 0.f;
    float4 acc = {0.f, 0.f, 0.f, 0.f};
    for (int j0 = lo; j0 < hi; j0 += CH1) {
        int sn[CH1];
        float x[CH1];
        sn[0] = esrc[j0];
#pragma unroll
        for (int t = 1; t < CH1; ++t) sn[t] = (j0 + t < hi) ? esrc[j0 + t] : sn[0];
#pragma unroll
        for (int t = 0; t < CH1; ++t) {
            float v = el[sn[t] * 8 + hh] + er_i;
            v = (v >= 0.f) ? v : NEG_SLOPE * v;
            x[t] = (j0 + t < hi) ? v : -INFINITY;
        }
        float M = x[0];
#pragma unroll
        for (int t = 1; t < CH1; ++t) M = fmaxf(M, x[t]);
        if (M > m) {
            float r = __expf(m - M);  // first chunk: exp(-inf)=0
            s *= r;
            acc.x *= r; acc.y *= r; acc.z *= r; acc.w *= r;
            m = M;
        }
        float w[CH1];
#pragma unroll
        for (int t = 0; t < CH1; ++t) {
            w[t] = __expf(x[t] - m);  // guarded slots: exp(-inf)=0
            s += w[t];
        }
        uint2 f[CH1];
#pragma unroll
        for (int t = 0; t < CH1; ++t)
            f[t] = *(const uint2*)(feat + (size_t)sn[t] * 256 + lane * 4);
#pragma unroll
        for (int t = 0; t < CH1; ++t) {
            acc.x += bflo(f[t].x) * w[t];
            acc.y += bfhi(f[t].x) * w[t];
            acc.z += bflo(f[t].y) * w[t];
            acc.w += bfhi(f[t].y) * w[t];
        }
    }
    float inv = 1.f / s;
    const float4 b = *(const float4*)(bias + lane * 4);
    float4 v = {acc.x * inv + b.x, acc.y * inv + b.y,
                acc.z * inv + b.z, acc.w * inv + b.w};
    v.x = (v.x > 0.f) ? v.x : (__expf(v.x) - 1.f);
    v.y = (v.y > 0.f) ? v.y : (__expf(v.y) - 1.f);
    v.z = (v.z > 0.f) ? v.z : (__expf(v.z) - 1.f);
    v.w = (v.w > 0.f) ? v.w : (__expf(v.w) - 1.f);
    *(float4*)(out + (size_t)i * 256 + lane * 4) = v;
}

// ---------------- layer-2 fused online-softmax aggregation ----------------

__global__ __launch_bounds__(256) void k_agg2(const unsigned short* __restrict__ feat2,
                                              const float* __restrict__ el2,
                                              const float* __restrict__ er2,
                                              const int* __restrict__ rp,
                                              const int* __restrict__ esrc,
                                              const float* __restrict__ b2,
                                              float* __restrict__ out) {
    int wid = threadIdx.x >> 6;
    int lane = threadIdx.x & 63;
    int i = blockIdx.x * 4 + wid;
    if (i >= NN) return;
    int g = lane >> 4;   // edge group 0..3
    int c = lane & 15;   // channel quad
    int lo = rp[i], hi = rp[i + 1];
    float er_i = er2[i];
    int sn_safe = esrc[lo];
    float m = -INFINITY, s = 0.f;
    float4 acc = {0.f, 0.f, 0.f, 0.f};
    for (int j0 = lo; j0 < hi; j0 += 8) {
        int ja = j0 + g, jb = j0 + 4 + g;
        int sna = (ja < hi) ? esrc[ja] : sn_safe;
        int snb = (jb < hi) ? esrc[jb] : sn_safe;
        float xa = el2[sna] + er_i;
        float xb = el2[snb] + er_i;
        xa = (xa >= 0.f) ? xa : NEG_SLOPE * xa;
        xb = (xb >= 0.f) ? xb : NEG_SLOPE * xb;
        if (ja >= hi) xa = -INFINITY;
        if (jb >= hi) xb = -INFINITY;
        float M = fmaxf(xa, xb);
        if (M > m) {
            float r = __expf(m - M);
            s *= r;
            acc.x *= r; acc.y *= r; acc.z *= r; acc.w *= r;
            m = M;
        }
        float wa = (ja < hi) ? __expf(xa - m) : 0.f;  // NaN guard: empty group m=-inf
        float wb = (jb < hi) ? __expf(xb - m) : 0.f;
        s += wa + wb;
        const uint2 fa = *(const uint2*)(feat2 + (size_t)sna * 64 + c * 4);
        const uint2 fb = *(const uint2*)(feat2 + (size_t)snb * 64 + c * 4);
        acc.x += bflo(fa.x) * wa + bflo(fb.x) * wb;
        acc.y += bfhi(fa.x) * wa + bfhi(fb.x) * wb;
        acc.z += bflo(fa.y) * wa + bflo(fb.y) * wb;
        acc.w += bfhi(fa.y) * wa + bfhi(fb.y) * wb;
    }
#pragma unroll
    for (int off = 16; off < 64; off <<= 1) {
        float mo = __shfl_xor(m, off);
        float so = __shfl_xor(s, off);
        float4 ao;
        ao.x = __shfl_xor(acc.x, off);
        ao.y = __shfl_xor(acc.y, off);
        ao.z = __shfl_xor(acc.z, off);
        ao.w = __shfl_xor(acc.w, off);
        float M = fmaxf(m, mo);
        float w0 = (m == -INFINITY) ? 0.f : __expf(m - M);
        float w1 = (mo == -INFINITY) ? 0.f : __expf(mo - M);
        s = s * w0 + so * w1;
        acc.x = acc.x * w0 + ao.x * w1;
        acc.y = acc.y * w0 + ao.y * w1;
        acc.z = acc.z * w0 + ao.z * w1;
        acc.w = acc.w * w0 + ao.w * w1;
        m = M;
    }
    if (g == 0) {
        float inv = 1.f / s;
        const float4 b = *(const float4*)(b2 + c * 4);
        float4 v = {acc.x * inv + b.x, acc.y * inv + b.y,
                    acc.z * inv + b.z, acc.w * inv + b.w};
        *(float4*)(out + (size_t)i * 64 + c * 4) = v;
    }
}

// ---------------- launch ----------------

extern "C" void kernel_launch(void* const* d_in, const int* in_sizes, int n_in,
                              void* d_out, int out_size, void* d_ws, size_t ws_size,
                              hipStream_t stream) {
    const float* h   = (const float*)d_in[0];
    const float* W1  = (const float*)d_in[1];
    const float* al1 = (const float*)d_in[2];
    const float* ar1 = (const float*)d_in[3];
    const float* b1  = (const float*)d_in[4];
    const float* W2  = (const float*)d_in[5];
    const float* al2 = (const float*)d_in[6];
    const float* ar2 = (const float*)d_in[7];
    const float* b2  = (const float*)d_in[8];
    const int* src   = (const int*)d_in[9];
    const int* dst   = (const int*)d_in[10];
    float* out = (float*)d_out;

    // workspace carve (~85 MB)
    float* fp = (float*)d_ws;
    float* h1  = fp; fp += (size_t)NN * 256;
    float* el1 = fp; fp += (size_t)NN * 8;
    float* er1 = fp; fp += (size_t)NN * 8;
    float* el2 = fp; fp += NN;
    float* er2 = fp; fp += NN;
    unsigned short* feat1 = (unsigned short*)fp;           // NN*256 bf16 (16B-aligned)
    unsigned short* feat2 = feat1;                          // aliases (feat1 dead after agg1)
    unsigned int* W1f = (unsigned int*)(feat1 + (size_t)NN * 256);  // 8192 x int4 = 128KB
    int* ip = (int*)(W1f + 8192 * 4);
    int* row_ptr = ip; ip += NN + 1;
    int* cnt  = ip; ip += NN;
    int* fill = ip; ip += NN;   // adjacent to cnt: single memset covers both
    int* esrc = ip; ip += EE;

    hipMemsetAsync(cnt, 0, sizeof(int) * 2 * NN, stream);

    // CSR by dst
    k_hist<<<(EE + 255) / 256, 256, 0, stream>>>(dst, cnt);
    k_scan<<<1, 1024, 0, stream>>>(cnt, row_ptr);
    k_scatter<<<(EE + 255) / 256, 256, 0, stream>>>(src, dst, row_ptr, fill, esrc);

    // layer 1: MFMA GEMM
    k_prepw<<<32, 256, 0, stream>>>(W1, W1f);
    k_mfma1<<<(3125 * 64 + 255) / 256, 256, 0, stream>>>(h, (const uint4*)W1f, feat1);
    k_el_er<8, 32><<<(NN * 8 + 255) / 256, 256, 0, stream>>>(feat1, al1, ar1, el1, er1);
    k_agg1<<<(NN + 3) / 4, 256, 0, stream>>>(feat1, el1, er1, row_ptr, esrc, b1, h1);

    // layer 2
    dim3 g2((NN + 63) / 64, 64 / 64);
    k_gemm<<<g2, 256, 0, stream>>>(h1, W2, feat2, NN, 64);
    k_el_er<1, 64><<<(NN + 255) / 256, 256, 0, stream>>>(feat2, al2, ar2, el2, er2);
    k_agg2<<<(NN + 3) / 4, 256, 0, stream>>>(feat2, el2, er2, row_ptr, esrc, b2, out);
}